// Round 5
// baseline (363.126 us; speedup 1.0000x reference)
//
#include <hip/hip_runtime.h>

#define N_NODES 100000
#define N_EDGES 1600000
#define D 64
#define NBLK 391                 // ceil(N_NODES/256) scan blocks
#define NPAD 100096              // 391*256

typedef unsigned short u16;
typedef short bf16x8 __attribute__((ext_vector_type(8)));
typedef short s16x4  __attribute__((ext_vector_type(4)));
typedef float f32x4  __attribute__((ext_vector_type(4)));

__device__ __forceinline__ float bf2f(u16 u) {
    unsigned v = (unsigned)u << 16;
    float f;
    __builtin_memcpy(&f, &v, 4);
    return f;
}
__device__ __forceinline__ u16 f2bf(float f) {
    unsigned u;
    __builtin_memcpy(&u, &f, 4);
    u = (u + 0x7FFFu + ((u >> 16) & 1u)) >> 16;
    return (u16)u;
}

// ---------------------------------------------------------------------------
// x (f32) -> xb (bf16), 4 elems/thread.
// ---------------------------------------------------------------------------
__global__ __launch_bounds__(256) void convert_kernel(
    const float* __restrict__ x, u16* __restrict__ xb)
{
    int i = blockIdx.x * 256 + threadIdx.x;
    float4 v = ((const float4*)x)[i];
    ushort4 o;
    o.x = f2bf(v.x); o.y = f2bf(v.y); o.z = f2bf(v.z); o.w = f2bf(v.w);
    ((ushort4*)xb)[i] = o;
}

// ---------------------------------------------------------------------------
// Pack W1/W2 (fp32 64x64) into bf16 MFMA B-fragment order.
// frag f = (layer*4 + ct)*2 + kf holds B[k=kf*32+quad*8+j][n=ct*16+(lane&15)]
// at u16 offset f*512 + lane*8 + j.
// ---------------------------------------------------------------------------
__global__ __launch_bounds__(256) void prep_weights_kernel(
    const float* __restrict__ W1, const float* __restrict__ W2,
    u16* __restrict__ Wf)
{
    int t = blockIdx.x * 256 + threadIdx.x;   // 16 frags * 64 lanes = 1024
    if (t >= 16 * 64) return;
    int f = t >> 6, lane = t & 63;
    int layer = f >> 3, ct = (f >> 1) & 3, kf = f & 1;
    const float* W = layer ? W2 : W1;
    int col = ct * 16 + (lane & 15);
    int krow = kf * 32 + (lane >> 4) * 8;
    u16* o = Wf + f * 512 + lane * 8;
#pragma unroll
    for (int j = 0; j < 8; ++j)
        o[j] = f2bf(W[(krow + j) * D + col]);
}

// ---------------------------------------------------------------------------
// CSR build, stage 1: degree histogram. 1 thread/edge, device-scope atomics
// to 100k counters (mean 16 hits/counter, time-spread -> near-zero
// contention; G12/m20: global atomicAdd is device-scope by default).
// ---------------------------------------------------------------------------
__global__ __launch_bounds__(256) void hist_kernel(
    const int* __restrict__ ei, int* __restrict__ cnt)
{
    int e = blockIdx.x * 256 + threadIdx.x;   // 6250*256 = 1600000 exact
    atomicAdd(&cnt[ei[N_EDGES + e]], 1);
}

// ---------------------------------------------------------------------------
// CSR build, stage 2a: per-256-chunk local exclusive scan + chunk totals.
// ---------------------------------------------------------------------------
__global__ __launch_bounds__(256) void scan_local_kernel(
    const int* __restrict__ cnt, int* __restrict__ eloc,
    int* __restrict__ btot)
{
    __shared__ int sc[256];
    int tid = threadIdx.x;
    int node = blockIdx.x * 256 + tid;
    int v = (node < N_NODES) ? cnt[node] : 0;
    sc[tid] = v;
    __syncthreads();
    for (int off = 1; off < 256; off <<= 1) {
        int t = (tid >= off) ? sc[tid - off] : 0;
        __syncthreads();
        sc[tid] += t;
        __syncthreads();
    }
    eloc[node] = sc[tid] - v;                 // exclusive within chunk
    if (tid == 255) btot[blockIdx.x] = sc[255];
}

// ---------------------------------------------------------------------------
// CSR build, stage 2b: exclusive scan of the 391 chunk totals (one block).
// ---------------------------------------------------------------------------
__global__ __launch_bounds__(512) void scan_base_kernel(
    const int* __restrict__ btot, int* __restrict__ bbase)
{
    __shared__ int sc[512];
    int tid = threadIdx.x;
    int v = (tid < NBLK) ? btot[tid] : 0;
    sc[tid] = v;
    __syncthreads();
    for (int off = 1; off < 512; off <<= 1) {
        int t = (tid >= off) ? sc[tid - off] : 0;
        __syncthreads();
        sc[tid] += t;
        __syncthreads();
    }
    bbase[tid] = sc[tid] - v;                 // exclusive
}

// ---------------------------------------------------------------------------
// CSR build, stage 2c: row_start = bbase + eloc; run = copy for the scatter.
// ---------------------------------------------------------------------------
__global__ __launch_bounds__(256) void scan_add_kernel(
    const int* __restrict__ eloc, const int* __restrict__ bbase,
    int* __restrict__ row_start, int* __restrict__ run)
{
    int node = blockIdx.x * 256 + threadIdx.x;
    int rs = bbase[blockIdx.x] + eloc[node];
    row_start[node] = rs;
    run[node] = rs;
}

// ---------------------------------------------------------------------------
// CSR build, stage 3: scatter src indices into per-dst segments.
// Within-segment order is nondeterministic (atomic race) — sum is
// order-independent up to f32 rounding noise.
// ---------------------------------------------------------------------------
__global__ __launch_bounds__(256) void scatter_kernel(
    const int* __restrict__ ei, int* __restrict__ run,
    int* __restrict__ sorted_src)
{
    int e = blockIdx.x * 256 + threadIdx.x;   // 6250*256 = 1600000 exact
    int src = ei[e];
    int dst = ei[N_EDGES + e];
    int pos = atomicAdd(&run[dst], 1);
    sorted_src[pos] = src;
}

// ---------------------------------------------------------------------------
// Gather aggregation (r1 version, verbatim mechanics): 8 nodes per wave,
// 8 lanes per node, 16B/lane. One global_load_dwordx4 retires 8 edges per
// wave instruction. Edge indices: coalesced per-lane load + ds_bpermute
// broadcast within the 8-lane group. Consecutive nodes per wave -> self-row
// loads, index segments, and the output store are contiguous. Tail edges pad
// to the zeroed dummy row N_NODES (L1-hot).
// ---------------------------------------------------------------------------
__global__ __launch_bounds__(256) void aggregate_kernel(
    const u16* __restrict__ xb, const int* __restrict__ cnt_arr,
    const int* __restrict__ row_start, const int* __restrict__ sorted_src,
    u16* __restrict__ xa)
{
    int tid  = threadIdx.x;
    int lane = tid & 63;
    int w    = tid >> 6;
    int g    = lane >> 3;        // group (node within wave)
    int k    = lane & 7;         // 16B chunk within row / edge slot in batch
    int node = blockIdx.x * 32 + w * 8 + g;   // 3125 blocks * 32 = 100000 exact

    int cnt  = cnt_arr[node];
    int base = row_start[node];

    // self-row init: acc = x[node]  (accl[i]=col k*8+2i, acch[i]=col k*8+2i+1)
    const uint4 sv = *(const uint4*)(xb + ((size_t)node * D + k * 8));
    float accl[4], acch[4];
#pragma unroll
    for (int i = 0; i < 4; ++i) {
        unsigned d = ((const unsigned*)&sv)[i];
        unsigned lo = d << 16, hi = d & 0xFFFF0000u;
        __builtin_memcpy(&accl[i], &lo, 4);
        __builtin_memcpy(&acch[i], &hi, 4);
    }

    // wave max degree across the 8 groups -> common trip count
    int mc = cnt;
    mc = max(mc, __shfl_xor(mc, 8));
    mc = max(mc, __shfl_xor(mc, 16));
    mc = max(mc, __shfl_xor(mc, 32));

    int lb4 = (lane & 56) << 2;  // byte addr of group's lane 0 for bpermute

    for (int c = 0; c < mc; c += 8) {
        // lane k holds edge c+k's source index for its group;
        // past-degree slots point at the zeroed dummy row N_NODES.
        int s = (c + k < cnt) ? sorted_src[base + c + k] : N_NODES;

        uint4 v[8];
#pragma unroll
        for (int j = 0; j < 8; ++j) {
            int idx = __builtin_amdgcn_ds_bpermute(lb4 + 4 * j, s);
            v[j] = *(const uint4*)(xb + (((size_t)(unsigned)idx) * D + (k << 3)));
        }
#pragma unroll
        for (int j = 0; j < 8; ++j) {
#pragma unroll
            for (int i = 0; i < 4; ++i) {
                unsigned d = ((const unsigned*)&v[j])[i];
                unsigned lo = d << 16, hi = d & 0xFFFF0000u;
                float fl, fh;
                __builtin_memcpy(&fl, &lo, 4);
                __builtin_memcpy(&fh, &hi, 4);
                accl[i] += fl;
                acch[i] += fh;
            }
        }
    }

    // pack to bf16 pairs and store this lane's 16B of the row
    unsigned out[4];
#pragma unroll
    for (int i = 0; i < 4; ++i) {
        unsigned b0 = f2bf(accl[i]);
        unsigned b1 = f2bf(acch[i]);
        out[i] = b0 | (b1 << 16);
    }
    *(uint4*)(xa + ((size_t)node * D + k * 8)) = *(const uint4*)out;
}

// ---------------------------------------------------------------------------
// MFMA MLP: out = [relu?]( relu(xa@W1+b1) @ W2 + b2 ), bf16 in, fp32 acc.
// Block = 256 = 4 waves; wave = 16 nodes x all 64 cols.
// A-frags (A[m=lane&15][k=quad*8+j], m120-verified) load DIRECTLY from
// global xa: one dwordx4 per K-half (wave covers a contiguous 2KB window).
// B-frags: prepacked Wf, one dwordx4 per frag. C/D layout (m89-verified):
// col=lane&15, row=quad*4+reg. Hidden u round-trips through WAVE-PRIVATE
// LDS rows (stride 136B -> layer-2 A-frag ds_read_b64 pairs, <=4-way
// aliased); no __syncthreads needed.
// ---------------------------------------------------------------------------
#define US 68   // u16 stride per node row (136 B)

template <int WRITE_BF16>
__global__ __launch_bounds__(256) void gin_mlp_kernel(
    const u16* __restrict__ xa, const u16* __restrict__ Wf,
    const float* __restrict__ b1, const float* __restrict__ b2,
    float* __restrict__ outf, u16* __restrict__ outb)
{
    __shared__ u16 us[64 * US];   // 8704 B

    int tid  = threadIdx.x;
    int lane = tid & 63;
    int w    = tid >> 6;
    int quad = lane >> 4;
    int l16  = lane & 15;
    int n0   = blockIdx.x * 64 + w * 16;

    // ---- layer 1: u = relu(xa @ W1 + b1) ----
    int arow = min(n0 + l16, N_NODES - 1);
    const u16* ab = xa + (size_t)arow * D + quad * 8;
    bf16x8 a0 = *(const bf16x8*)ab;          // k = quad*8+j
    bf16x8 a1 = *(const bf16x8*)(ab + 32);   // k = 32+quad*8+j

    f32x4 acc[4];
#pragma unroll
    for (int ct = 0; ct < 4; ++ct) {
        float bv = b1[ct * 16 + l16];
        acc[ct] = (f32x4){bv, bv, bv, bv};
        bf16x8 bf0 = *(const bf16x8*)(Wf + (size_t)((0 * 4 + ct) * 2 + 0) * 512 + lane * 8);
        bf16x8 bf1 = *(const bf16x8*)(Wf + (size_t)((0 * 4 + ct) * 2 + 1) * 512 + lane * 8);
        acc[ct] = __builtin_amdgcn_mfma_f32_16x16x32_bf16(a0, bf0, acc[ct], 0, 0, 0);
        acc[ct] = __builtin_amdgcn_mfma_f32_16x16x32_bf16(a1, bf1, acc[ct], 0, 0, 0);
    }

    // relu -> bf16 -> wave-private LDS rows (C-layout: row=quad*4+r, col)
#pragma unroll
    for (int ct = 0; ct < 4; ++ct)
#pragma unroll
        for (int r = 0; r < 4; ++r)
            us[(w * 16 + quad * 4 + r) * US + ct * 16 + l16] =
                f2bf(fmaxf(acc[ct][r], 0.f));

    // ---- layer 2: v = u @ W2 + b2 ----
    const u16* ub = &us[(w * 16 + l16) * US + quad * 8];
    s16x4 lo0 = *(const s16x4*)ub;
    s16x4 hi0 = *(const s16x4*)(ub + 4);
    s16x4 lo1 = *(const s16x4*)(ub + 32);
    s16x4 hi1 = *(const s16x4*)(ub + 36);
    bf16x8 u0 = __builtin_shufflevector(lo0, hi0, 0, 1, 2, 3, 4, 5, 6, 7);
    bf16x8 u1 = __builtin_shufflevector(lo1, hi1, 0, 1, 2, 3, 4, 5, 6, 7);

#pragma unroll
    for (int ct = 0; ct < 4; ++ct) {
        float bv = b2[ct * 16 + l16];
        acc[ct] = (f32x4){bv, bv, bv, bv};
        bf16x8 bf0 = *(const bf16x8*)(Wf + (size_t)((1 * 4 + ct) * 2 + 0) * 512 + lane * 8);
        bf16x8 bf1 = *(const bf16x8*)(Wf + (size_t)((1 * 4 + ct) * 2 + 1) * 512 + lane * 8);
        acc[ct] = __builtin_amdgcn_mfma_f32_16x16x32_bf16(u0, bf0, acc[ct], 0, 0, 0);
        acc[ct] = __builtin_amdgcn_mfma_f32_16x16x32_bf16(u1, bf1, acc[ct], 0, 0, 0);
    }

    // epilogue (C-layout scatter; 16-lane groups write contiguous runs)
#pragma unroll
    for (int r = 0; r < 4; ++r) {
        int node = n0 + quad * 4 + r;
        if (node >= N_NODES) continue;
#pragma unroll
        for (int ct = 0; ct < 4; ++ct) {
            if (WRITE_BF16)
                outb[(size_t)node * D + ct * 16 + l16] = f2bf(fmaxf(acc[ct][r], 0.f));
            else
                outf[(size_t)node * D + ct * 16 + l16] = acc[ct][r];
        }
    }
}

extern "C" void kernel_launch(void* const* d_in, const int* in_sizes, int n_in,
                              void* d_out, int out_size, void* d_ws, size_t ws_size,
                              hipStream_t stream)
{
    const float* x  = (const float*)d_in[0];
    const int*   ei = (const int*)d_in[1];
    const float* W1 = (const float*)d_in[2];
    const float* b1 = (const float*)d_in[3];
    const float* W2 = (const float*)d_in[4];
    const float* b2 = (const float*)d_in[5];
    float* out = (float*)d_out;

    // workspace (~34 MB):
    //   cnt(100096) | row_start(100096) | run(100096) | eloc(100096)
    //   | btot(512) | bbase(512) | sorted_src(1.6M int)
    //   | Wf(8192 u16) | xa ((N+1) rows bf16) | xb ((N+1) rows bf16, = hb)
    int* cnt_arr    = (int*)d_ws;
    int* row_start  = cnt_arr + NPAD;
    int* run        = row_start + NPAD;
    int* eloc       = run + NPAD;
    int* btot       = eloc + NPAD;
    int* bbase      = btot + 512;
    int* sorted_src = bbase + 512;
    u16* Wf         = (u16*)(sorted_src + N_EDGES);
    u16* xa_b       = Wf + 8192;
    u16* xb_b       = xa_b + (size_t)(N_NODES + 1) * D;

    const int edge_blocks = N_EDGES / 256;          // 6250 exact
    const int agg_blocks  = (N_NODES + 31) / 32;    // 3125 (8 nodes/wave)
    const int mlp_blocks  = (N_NODES + 63) / 64;    // 1563

    // ---- prep: zero counters + dummy row, x -> bf16, weights ----
    hipMemsetAsync(cnt_arr, 0, NPAD * sizeof(int), stream);
    hipMemsetAsync(xb_b + (size_t)N_NODES * D, 0, D * sizeof(u16), stream);
    convert_kernel<<<(N_NODES * D / 4) / 256, 256, 0, stream>>>(x, xb_b);
    prep_weights_kernel<<<4, 256, 0, stream>>>(W1, W2, Wf);

    // ---- CSR build: hist -> 3-stage scan -> scatter ----
    hist_kernel<<<edge_blocks, 256, 0, stream>>>(ei, cnt_arr);
    scan_local_kernel<<<NBLK, 256, 0, stream>>>(cnt_arr, eloc, btot);
    scan_base_kernel<<<1, 512, 0, stream>>>(btot, bbase);
    scan_add_kernel<<<NBLK, 256, 0, stream>>>(eloc, bbase, row_start, run);
    scatter_kernel<<<edge_blocks, 256, 0, stream>>>(ei, run, sorted_src);

    // ---- layer 1: hb(xb_b) = relu(MLP(xb + gather(xb))) ----
    aggregate_kernel<<<agg_blocks, 256, 0, stream>>>(xb_b, cnt_arr, row_start, sorted_src, xa_b);
    gin_mlp_kernel<1><<<mlp_blocks, 256, 0, stream>>>(xa_b, Wf, b1, b2, nullptr, xb_b);

    // ---- layer 2: out = MLP(hb + gather(hb)) ----
    aggregate_kernel<<<agg_blocks, 256, 0, stream>>>(xb_b, cnt_arr, row_start, sorted_src, xa_b);
    gin_mlp_kernel<0><<<mlp_blocks, 256, 0, stream>>>(xa_b, Wf, b1, b2, out, nullptr);
}

// Round 6
// 219.559 us; speedup vs baseline: 1.6539x; 1.6539x over previous
//
#include <hip/hip_runtime.h>

#define N_NODES 100000
#define N_EDGES 1600000
#define D 64
#define NBUCKET 391              // ceil(N_NODES/256), bucket = 256 dst nodes
#define QCAP_B 4800              // per-bucket queue cap (mean 4096, sd ~64)
#define EPB 4096                 // edges per sort block
#define SORT_BLOCKS 391          // ceil(N_EDGES/EPB)

typedef unsigned short u16;
typedef short bf16x8 __attribute__((ext_vector_type(8)));
typedef short s16x4  __attribute__((ext_vector_type(4)));
typedef float f32x4  __attribute__((ext_vector_type(4)));

__device__ __forceinline__ float bf2f(u16 u) {
    unsigned v = (unsigned)u << 16;
    float f;
    __builtin_memcpy(&f, &v, 4);
    return f;
}
__device__ __forceinline__ u16 f2bf(float f) {
    unsigned u;
    __builtin_memcpy(&u, &f, 4);
    u = (u + 0x7FFFu + ((u >> 16) & 1u)) >> 16;
    return (u16)u;
}

// acc += selected bf16 half of dw (sel = packed bf16 {1.0,0} or {0,1.0}).
// v_dot2_f32_bf16: D = S0.lo*S1.lo + S0.hi*S1.hi + S2, products in f32 ->
// exact same math as unpack+f32 add, at 1 VALU op instead of 2.
#define DOT2ACC(accf, dw, sel) \
    asm("v_dot2_f32_bf16 %0, %1, %2, %0" : "+v"(accf) : "v"(dw), "v"(sel))

// ---------------------------------------------------------------------------
// x (f32) -> xb (bf16), 4 elems/thread.
// ---------------------------------------------------------------------------
__global__ __launch_bounds__(256) void convert_kernel(
    const float* __restrict__ x, u16* __restrict__ xb)
{
    int i = blockIdx.x * 256 + threadIdx.x;
    float4 v = ((const float4*)x)[i];
    ushort4 o;
    o.x = f2bf(v.x); o.y = f2bf(v.y); o.z = f2bf(v.z); o.w = f2bf(v.w);
    ((ushort4*)xb)[i] = o;
}

// ---------------------------------------------------------------------------
// Pack W1/W2 (fp32 64x64) into bf16 MFMA B-fragment order.
// frag f = (layer*4 + ct)*2 + kf holds B[k=kf*32+quad*8+j][n=ct*16+(lane&15)]
// at u16 offset f*512 + lane*8 + j.
// ---------------------------------------------------------------------------
__global__ __launch_bounds__(256) void prep_weights_kernel(
    const float* __restrict__ W1, const float* __restrict__ W2,
    u16* __restrict__ Wf)
{
    int t = blockIdx.x * 256 + threadIdx.x;   // 16 frags * 64 lanes = 1024
    if (t >= 16 * 64) return;
    int f = t >> 6, lane = t & 63;
    int layer = f >> 3, ct = (f >> 1) & 3, kf = f & 1;
    const float* W = layer ? W2 : W1;
    int col = ct * 16 + (lane & 15);
    int krow = kf * 32 + (lane >> 4) * 8;
    u16* o = Wf + f * 512 + lane * 8;
#pragma unroll
    for (int j = 0; j < 8; ++j)
        o[j] = f2bf(W[(krow + j) * D + col]);
}

// ---------------------------------------------------------------------------
// Block-level counting sort of 4096 edges into 391 bucket queues (r9/r10).
// Entry packs (dst&255)<<17 | src.
// ---------------------------------------------------------------------------
__global__ __launch_bounds__(256) void sort_kernel(
    const int* __restrict__ ei, int* __restrict__ qtail,
    unsigned* __restrict__ queue)
{
    __shared__ int cnt[512];
    __shared__ int scan[512];
    __shared__ int gbase[512];
    __shared__ int run[512];
    __shared__ unsigned staged[EPB];
    __shared__ int gposa[EPB];

    int tid = threadIdx.x;
    int e0 = blockIdx.x * EPB;

    cnt[tid] = 0; cnt[tid + 256] = 0;
    run[tid] = 0; run[tid + 256] = 0;
    __syncthreads();

    for (int i = tid; i < EPB; i += 256) {
        int e = e0 + i;
        if (e < N_EDGES) {
            int dst = ei[N_EDGES + e];
            atomicAdd(&cnt[dst >> 8], 1);
        }
    }
    __syncthreads();
    scan[tid] = cnt[tid]; scan[tid + 256] = cnt[tid + 256];
    __syncthreads();
    for (int off = 1; off < 512; off <<= 1) {
        int v1 = (tid >= off) ? scan[tid - off] : 0;
        int v2 = scan[tid + 256 - off];
        __syncthreads();
        scan[tid] += v1;
        scan[tid + 256] += v2;
        __syncthreads();
    }
    if (tid < NBUCKET && cnt[tid] > 0)
        gbase[tid] = atomicAdd(&qtail[tid], cnt[tid]);
    int b2 = tid + 256;
    if (b2 < NBUCKET && cnt[b2] > 0)
        gbase[b2] = atomicAdd(&qtail[b2], cnt[b2]);
    __syncthreads();

    for (int i = tid; i < EPB; i += 256) {
        int e = e0 + i;
        if (e < N_EDGES) {
            int dst = ei[N_EDGES + e];
            int src = ei[e];
            int b = dst >> 8;
            int r = atomicAdd(&run[b], 1);
            int slot = scan[b] - cnt[b] + r;
            staged[slot] = ((unsigned)(dst & 255) << 17) | (unsigned)src;
            int gp = gbase[b] + r;
            gposa[slot] = (gp < QCAP_B) ? b * QCAP_B + gp : -1;
        }
    }
    __syncthreads();

    int total = scan[511];
    for (int i = tid; i < total; i += 256) {
        int gp = gposa[i];
        if (gp >= 0) queue[gp] = staged[i];
    }
}

// ---------------------------------------------------------------------------
// Per-bucket LDS counting sort -> exact CSR. Zero global atomics (r10).
// ---------------------------------------------------------------------------
__global__ __launch_bounds__(256) void bin3_kernel(
    const unsigned* __restrict__ queue, const int* __restrict__ qtail,
    int* __restrict__ cnt_out, int* __restrict__ row_start,
    int* __restrict__ sorted_src)
{
    __shared__ int cnt[256];
    __shared__ int scanv[256];
    __shared__ int run[256];
    __shared__ unsigned staged[QCAP_B];

    int tid = threadIdx.x;
    int b = blockIdx.x;
    cnt[tid] = 0; run[tid] = 0;
    __syncthreads();

    int n = min(qtail[b], QCAP_B);
    const unsigned* q = queue + (size_t)b * QCAP_B;

    for (int i = tid; i < n; i += 256) {
        unsigned e = q[i];
        staged[i] = e;
        atomicAdd(&cnt[e >> 17], 1);
    }
    __syncthreads();
    scanv[tid] = cnt[tid];
    __syncthreads();
    for (int off = 1; off < 256; off <<= 1) {
        int v = (tid >= off) ? scanv[tid - off] : 0;
        __syncthreads();
        scanv[tid] += v;
        __syncthreads();
    }

    int gb = b * QCAP_B;
    int node = b * 256 + tid;
    if (node < N_NODES) {
        cnt_out[node] = cnt[tid];
        row_start[node] = gb + scanv[tid] - cnt[tid];
    }

    for (int i = tid; i < n; i += 256) {
        unsigned e = staged[i];
        int r = (int)(e >> 17);
        int k = atomicAdd(&run[r], 1);
        int pos = gb + (scanv[r] - cnt[r]) + k;
        sorted_src[pos] = (int)(e & 0x1FFFFu);
    }
}

// ---------------------------------------------------------------------------
// Gather aggregation v5: r1 mechanics (8 nodes/wave, 8 lanes/node, coalesced
// per-lane index load + ds_bpermute broadcast + ILP-8 dwordx4 gathers,
// consecutive nodes -> contiguous self-rows/index-segments/output-store),
// with two latency/issue cuts:
//   1. v_dot2_f32_bf16 accumulate: 1 VALU/column instead of unpack+add (2).
//      selector {1,0} picks the low bf16, {0,1} the high; products are f32
//      -> bitwise-identical math to the old unpack path.
//   2. 1-deep software pipeline on the index load (batch c+8 prefetched
//      while batch c gathers).
// Tail edges pad to the zeroed dummy row N_NODES (L1-hot).
// ---------------------------------------------------------------------------
__global__ __launch_bounds__(256) void aggregate_kernel(
    const u16* __restrict__ xb, const int* __restrict__ cnt_arr,
    const int* __restrict__ row_start, const int* __restrict__ sorted_src,
    u16* __restrict__ xa)
{
    int tid  = threadIdx.x;
    int lane = tid & 63;
    int w    = tid >> 6;
    int g    = lane >> 3;        // group (node within wave)
    int k    = lane & 7;         // 16B chunk within row / edge slot in batch
    int node = blockIdx.x * 32 + w * 8 + g;   // 3125 blocks * 32 = 100000 exact

    int cnt  = cnt_arr[node];
    int base = row_start[node];

    // self-row init: acc = x[node]  (accl[i]=col k*8+2i, acch[i]=col k*8+2i+1)
    const uint4 sv = *(const uint4*)(xb + ((size_t)node * D + k * 8));
    float accl[4], acch[4];
#pragma unroll
    for (int i = 0; i < 4; ++i) {
        unsigned d = ((const unsigned*)&sv)[i];
        unsigned lo = d << 16, hi = d & 0xFFFF0000u;
        __builtin_memcpy(&accl[i], &lo, 4);
        __builtin_memcpy(&acch[i], &hi, 4);
    }

    // wave max degree across the 8 groups -> common trip count
    int mc = cnt;
    mc = max(mc, __shfl_xor(mc, 8));
    mc = max(mc, __shfl_xor(mc, 16));
    mc = max(mc, __shfl_xor(mc, 32));

    int lb4 = (lane & 56) << 2;  // byte addr of group's lane 0 for bpermute

    unsigned sel_lo = 0x00003F80u;   // bf16 {1.0, 0}
    unsigned sel_hi = 0x3F800000u;   // bf16 {0, 1.0}

    // pipelined index load: lane k holds edge c+k of its group's node
    int s_next = (k < cnt) ? sorted_src[base + k] : N_NODES;

    for (int c = 0; c < mc; c += 8) {
        int s_vec = s_next;
        int c2 = c + 8;
        if (c2 < mc)
            s_next = (c2 + k < cnt) ? sorted_src[base + c2 + k] : N_NODES;

        uint4 v[8];
#pragma unroll
        for (int j = 0; j < 8; ++j) {
            int idx = __builtin_amdgcn_ds_bpermute(lb4 + 4 * j, s_vec);
            v[j] = *(const uint4*)(xb + (((size_t)(unsigned)idx) * D + (k << 3)));
        }
#pragma unroll
        for (int j = 0; j < 8; ++j) {
#pragma unroll
            for (int i = 0; i < 4; ++i) {
                unsigned d = ((const unsigned*)&v[j])[i];
                DOT2ACC(accl[i], d, sel_lo);
                DOT2ACC(acch[i], d, sel_hi);
            }
        }
    }

    // pack to bf16 pairs and store this lane's 16B of the row
    unsigned out[4];
#pragma unroll
    for (int i = 0; i < 4; ++i) {
        unsigned b0 = f2bf(accl[i]);
        unsigned b1 = f2bf(acch[i]);
        out[i] = b0 | (b1 << 16);
    }
    *(uint4*)(xa + ((size_t)node * D + k * 8)) = *(const uint4*)out;
}

// ---------------------------------------------------------------------------
// MFMA MLP: out = [relu?]( relu(xa@W1+b1) @ W2 + b2 ), bf16 in, fp32 acc.
// Block = 256 = 4 waves; wave = 16 nodes x all 64 cols.
// A-frags (A[m=lane&15][k=quad*8+j], m120-verified) load DIRECTLY from
// global xa: one dwordx4 per K-half (wave covers a contiguous 2KB window).
// B-frags: prepacked Wf, one dwordx4 per frag. C/D layout (m89-verified):
// col=lane&15, row=quad*4+reg. Hidden u round-trips through WAVE-PRIVATE
// LDS rows (stride 136B -> layer-2 A-frag ds_read_b64 pairs, <=4-way
// aliased); no __syncthreads needed.
// ---------------------------------------------------------------------------
#define US 68   // u16 stride per node row (136 B)

template <int WRITE_BF16>
__global__ __launch_bounds__(256) void gin_mlp_kernel(
    const u16* __restrict__ xa, const u16* __restrict__ Wf,
    const float* __restrict__ b1, const float* __restrict__ b2,
    float* __restrict__ outf, u16* __restrict__ outb)
{
    __shared__ u16 us[64 * US];   // 8704 B

    int tid  = threadIdx.x;
    int lane = tid & 63;
    int w    = tid >> 6;
    int quad = lane >> 4;
    int l16  = lane & 15;
    int n0   = blockIdx.x * 64 + w * 16;

    // ---- layer 1: u = relu(xa @ W1 + b1) ----
    int arow = min(n0 + l16, N_NODES - 1);
    const u16* ab = xa + (size_t)arow * D + quad * 8;
    bf16x8 a0 = *(const bf16x8*)ab;          // k = quad*8+j
    bf16x8 a1 = *(const bf16x8*)(ab + 32);   // k = 32+quad*8+j

    f32x4 acc[4];
#pragma unroll
    for (int ct = 0; ct < 4; ++ct) {
        float bv = b1[ct * 16 + l16];
        acc[ct] = (f32x4){bv, bv, bv, bv};
        bf16x8 bf0 = *(const bf16x8*)(Wf + (size_t)((0 * 4 + ct) * 2 + 0) * 512 + lane * 8);
        bf16x8 bf1 = *(const bf16x8*)(Wf + (size_t)((0 * 4 + ct) * 2 + 1) * 512 + lane * 8);
        acc[ct] = __builtin_amdgcn_mfma_f32_16x16x32_bf16(a0, bf0, acc[ct], 0, 0, 0);
        acc[ct] = __builtin_amdgcn_mfma_f32_16x16x32_bf16(a1, bf1, acc[ct], 0, 0, 0);
    }

    // relu -> bf16 -> wave-private LDS rows (C-layout: row=quad*4+r, col)
#pragma unroll
    for (int ct = 0; ct < 4; ++ct)
#pragma unroll
        for (int r = 0; r < 4; ++r)
            us[(w * 16 + quad * 4 + r) * US + ct * 16 + l16] =
                f2bf(fmaxf(acc[ct][r], 0.f));

    // ---- layer 2: v = u @ W2 + b2 ----
    const u16* ub = &us[(w * 16 + l16) * US + quad * 8];
    s16x4 lo0 = *(const s16x4*)ub;
    s16x4 hi0 = *(const s16x4*)(ub + 4);
    s16x4 lo1 = *(const s16x4*)(ub + 32);
    s16x4 hi1 = *(const s16x4*)(ub + 36);
    bf16x8 u0 = __builtin_shufflevector(lo0, hi0, 0, 1, 2, 3, 4, 5, 6, 7);
    bf16x8 u1 = __builtin_shufflevector(lo1, hi1, 0, 1, 2, 3, 4, 5, 6, 7);

#pragma unroll
    for (int ct = 0; ct < 4; ++ct) {
        float bv = b2[ct * 16 + l16];
        acc[ct] = (f32x4){bv, bv, bv, bv};
        bf16x8 bf0 = *(const bf16x8*)(Wf + (size_t)((1 * 4 + ct) * 2 + 0) * 512 + lane * 8);
        bf16x8 bf1 = *(const bf16x8*)(Wf + (size_t)((1 * 4 + ct) * 2 + 1) * 512 + lane * 8);
        acc[ct] = __builtin_amdgcn_mfma_f32_16x16x32_bf16(u0, bf0, acc[ct], 0, 0, 0);
        acc[ct] = __builtin_amdgcn_mfma_f32_16x16x32_bf16(u1, bf1, acc[ct], 0, 0, 0);
    }

    // epilogue (C-layout scatter; 16-lane groups write contiguous runs)
#pragma unroll
    for (int r = 0; r < 4; ++r) {
        int node = n0 + quad * 4 + r;
        if (node >= N_NODES) continue;
#pragma unroll
        for (int ct = 0; ct < 4; ++ct) {
            if (WRITE_BF16)
                outb[(size_t)node * D + ct * 16 + l16] = f2bf(fmaxf(acc[ct][r], 0.f));
            else
                outf[(size_t)node * D + ct * 16 + l16] = acc[ct][r];
        }
    }
}

extern "C" void kernel_launch(void* const* d_in, const int* in_sizes, int n_in,
                              void* d_out, int out_size, void* d_ws, size_t ws_size,
                              hipStream_t stream)
{
    const float* x  = (const float*)d_in[0];
    const int*   ei = (const int*)d_in[1];
    const float* W1 = (const float*)d_in[2];
    const float* b1 = (const float*)d_in[3];
    const float* W2 = (const float*)d_in[4];
    const float* b2 = (const float*)d_in[5];
    float* out = (float*)d_out;

    // workspace (~41.5 MB):
    //   qtail(512) | cnt(100096) | row_start(100096)
    //   queue (391*4800 u32) | sorted_src (391*4800 int)
    //   Wf (8192 u16) | xa (N rows bf16) | xb ((N+1) rows bf16, also holds hb)
    int* qtail      = (int*)d_ws;
    int* cnt_arr    = qtail + 512;
    int* row_start  = cnt_arr + 100096;
    unsigned* queue = (unsigned*)(row_start + 100096);
    int* sorted_src = (int*)(queue + (size_t)NBUCKET * QCAP_B);
    u16* Wf         = (u16*)(sorted_src + (size_t)NBUCKET * QCAP_B);
    u16* xa_b       = Wf + 8192;
    u16* xb_b       = xa_b + (size_t)N_NODES * D;

    const int agg_blocks = (N_NODES + 31) / 32;     // 3125 (8 nodes/wave)
    const int mlp_blocks = (N_NODES + 63) / 64;     // 1563

    // ---- prep: qtail zero, dummy zero row, x -> bf16, weights, sort, CSR ----
    hipMemsetAsync(qtail, 0, 512 * sizeof(int), stream);
    hipMemsetAsync(xb_b + (size_t)N_NODES * D, 0, D * sizeof(u16), stream);
    convert_kernel<<<(N_NODES * D / 4) / 256, 256, 0, stream>>>(x, xb_b);
    prep_weights_kernel<<<4, 256, 0, stream>>>(W1, W2, Wf);
    sort_kernel<<<SORT_BLOCKS, 256, 0, stream>>>(ei, qtail, queue);
    bin3_kernel<<<NBUCKET, 256, 0, stream>>>(queue, qtail, cnt_arr, row_start, sorted_src);

    // ---- layer 1: hb(xb_b) = relu(MLP(xb + gather(xb))) ----
    aggregate_kernel<<<agg_blocks, 256, 0, stream>>>(xb_b, cnt_arr, row_start, sorted_src, xa_b);
    gin_mlp_kernel<1><<<mlp_blocks, 256, 0, stream>>>(xa_b, Wf, b1, b2, nullptr, xb_b);

    // ---- layer 2: out = MLP(hb + gather(hb)) ----
    aggregate_kernel<<<agg_blocks, 256, 0, stream>>>(xb_b, cnt_arr, row_start, sorted_src, xa_b);
    gin_mlp_kernel<0><<<mlp_blocks, 256, 0, stream>>>(xa_b, Wf, b1, b2, out, nullptr);
}

// Round 7
// 198.221 us; speedup vs baseline: 1.8319x; 1.1076x over previous
//
#include <hip/hip_runtime.h>

#define N_NODES 100000
#define N_EDGES 1600000
#define D 64
#define NBUCKET 391              // ceil(N_NODES/256), bucket = 256 dst nodes
#define QCAP_B 4800              // per-bucket queue cap (mean 4096, sd ~64)
#define EPB 4096                 // edges per sort block
#define SORT_BLOCKS 391          // ceil(N_EDGES/EPB)

typedef unsigned short u16;
typedef short bf16x8 __attribute__((ext_vector_type(8)));
typedef short s16x4  __attribute__((ext_vector_type(4)));
typedef float f32x4  __attribute__((ext_vector_type(4)));

__device__ __forceinline__ float bf2f(u16 u) {
    unsigned v = (unsigned)u << 16;
    float f;
    __builtin_memcpy(&f, &v, 4);
    return f;
}
__device__ __forceinline__ u16 f2bf(float f) {
    unsigned u;
    __builtin_memcpy(&u, &f, 4);
    u = (u + 0x7FFFu + ((u >> 16) & 1u)) >> 16;
    return (u16)u;
}

// ---------------------------------------------------------------------------
// x (f32) -> xb (bf16), 4 elems/thread. Extra block (blockIdx==6250) folds in
// the tiny prep work: qtail zero, dummy-row zero, W1/W2 -> bf16 frag pack.
// ---------------------------------------------------------------------------
__global__ __launch_bounds__(256) void convert_kernel(
    const float* __restrict__ x, u16* __restrict__ xb,
    const float* __restrict__ W1, const float* __restrict__ W2,
    u16* __restrict__ Wf, int* __restrict__ qtail)
{
    int tid = threadIdx.x;
    if (blockIdx.x < 6250) {
        int i = blockIdx.x * 256 + tid;
        float4 v = ((const float4*)x)[i];
        ushort4 o;
        o.x = f2bf(v.x); o.y = f2bf(v.y); o.z = f2bf(v.z); o.w = f2bf(v.w);
        ((ushort4*)xb)[i] = o;
        return;
    }
    // misc block: qtail[0..511] = 0; dummy row N_NODES = 0; weight pack.
    qtail[tid] = 0;
    qtail[tid + 256] = 0;
    if (tid < 32)
        ((unsigned*)(xb + (size_t)N_NODES * D))[tid] = 0;
#pragma unroll
    for (int t = tid; t < 16 * 64; t += 256) {
        int f = t >> 6, lane = t & 63;
        int layer = f >> 3, ct = (f >> 1) & 3, kf = f & 1;
        const float* W = layer ? W2 : W1;
        int col = ct * 16 + (lane & 15);
        int krow = kf * 32 + (lane >> 4) * 8;
        u16* o = Wf + f * 512 + lane * 8;
#pragma unroll
        for (int j = 0; j < 8; ++j)
            o[j] = f2bf(W[(krow + j) * D + col]);
    }
}

// ---------------------------------------------------------------------------
// Block-level counting sort of 4096 edges into 391 bucket queues.
// v2 schedule: 1024 threads (4 iters/pass instead of 16), wave-shfl scan
// (5 barriers instead of ~25). Entry packs (dst&255)<<17 | src.
// ---------------------------------------------------------------------------
__global__ __launch_bounds__(1024) void sort_kernel(
    const int* __restrict__ ei, int* __restrict__ qtail,
    unsigned* __restrict__ queue)
{
    __shared__ int cnt[512];
    __shared__ int base_s[512];
    __shared__ int gbase[512];
    __shared__ int run[512];
    __shared__ unsigned staged[EPB];
    __shared__ int gposa[EPB];
    __shared__ int wpart[8];
    __shared__ int tot_s;

    int tid = threadIdx.x;
    int e0 = blockIdx.x * EPB;
    int lane = tid & 63, wv = tid >> 6;

    if (tid < 512) { cnt[tid] = 0; run[tid] = 0; }
    __syncthreads();

    // ---- hist: 4 iters ----
    for (int i = tid; i < EPB; i += 1024) {
        int e = e0 + i;
        if (e < N_EDGES)
            atomicAdd(&cnt[ei[N_EDGES + e] >> 8], 1);
    }
    __syncthreads();

    // ---- 512-wide exclusive scan: 8 waves shfl-scan 64 each + combine ----
    int inc = 0, v = 0;
    if (tid < 512) {
        v = cnt[tid];
        inc = v;
        for (int off = 1; off < 64; off <<= 1) {
            int t = __shfl_up(inc, off);
            if (lane >= off) inc += t;
        }
        if (lane == 63) wpart[wv] = inc;
    }
    __syncthreads();
    if (tid < 64) {
        int p = (lane < 8) ? wpart[lane] : 0;
        int ps = p;
        for (int off = 1; off < 8; off <<= 1) {
            int t = __shfl_up(ps, off);
            if (lane >= off) ps += t;
        }
        if (lane < 8) wpart[lane] = ps - p;   // exclusive wave base
    }
    __syncthreads();
    if (tid < 512) {
        base_s[tid] = wpart[wv] + inc - v;    // exclusive prefix
        if (tid == 511) tot_s = wpart[7] + inc;
    }
    // ---- reserve global queue space (one atomic per nonempty bucket) ----
    if (tid < NBUCKET && cnt[tid] > 0)
        gbase[tid] = atomicAdd(&qtail[tid], cnt[tid]);
    __syncthreads();

    // ---- scatter into bucket-sorted LDS staging: 4 iters (ei re-read
    // is L2-hot from the hist pass) ----
    for (int i = tid; i < EPB; i += 1024) {
        int e = e0 + i;
        if (e < N_EDGES) {
            int dst = ei[N_EDGES + e];
            int src = ei[e];
            int b = dst >> 8;
            int r = atomicAdd(&run[b], 1);
            int slot = base_s[b] + r;
            staged[slot] = ((unsigned)(dst & 255) << 17) | (unsigned)src;
            int gp = gbase[b] + r;
            gposa[slot] = (gp < QCAP_B) ? b * QCAP_B + gp : -1;
        }
    }
    __syncthreads();

    // ---- copy out (bucket-contiguous runs): 4 iters ----
    int total = tot_s;
    for (int i = tid; i < total; i += 1024) {
        int gp = gposa[i];
        if (gp >= 0) queue[gp] = staged[i];
    }
}

// ---------------------------------------------------------------------------
// Per-bucket LDS counting sort -> exact CSR. Zero global atomics.
// v2 schedule: 1024 threads, wave-shfl scan (5 barriers instead of ~20).
// ---------------------------------------------------------------------------
__global__ __launch_bounds__(1024) void bin3_kernel(
    const unsigned* __restrict__ queue, const int* __restrict__ qtail,
    int* __restrict__ cnt_out, int* __restrict__ row_start,
    int* __restrict__ sorted_src)
{
    __shared__ int cnt[256];
    __shared__ int ebase[256];
    __shared__ int run[256];
    __shared__ unsigned staged[QCAP_B];
    __shared__ int wpart[8];

    int tid = threadIdx.x;
    int b = blockIdx.x;
    int lane = tid & 63, wv = tid >> 6;

    if (tid < 256) { cnt[tid] = 0; run[tid] = 0; }
    __syncthreads();

    int n = min(qtail[b], QCAP_B);
    const unsigned* q = queue + (size_t)b * QCAP_B;

    // ---- stage + hist: ~4 iters ----
    for (int i = tid; i < n; i += 1024) {
        unsigned e = q[i];
        staged[i] = e;
        atomicAdd(&cnt[e >> 17], 1);
    }
    __syncthreads();

    // ---- 256-wide exclusive scan: 4 waves shfl-scan + combine ----
    int inc = 0, v = 0;
    if (tid < 256) {
        v = cnt[tid];
        inc = v;
        for (int off = 1; off < 64; off <<= 1) {
            int t = __shfl_up(inc, off);
            if (lane >= off) inc += t;
        }
        if (lane == 63) wpart[wv] = inc;
    }
    __syncthreads();
    if (tid < 64) {
        int p = (lane < 4) ? wpart[lane] : 0;
        int ps = p;
        for (int off = 1; off < 4; off <<= 1) {
            int t = __shfl_up(ps, off);
            if (lane >= off) ps += t;
        }
        if (lane < 4) wpart[lane] = ps - p;
    }
    __syncthreads();

    int gb = b * QCAP_B;
    if (tid < 256) {
        int eb = wpart[wv] + inc - v;         // exclusive prefix
        ebase[tid] = eb;
        int node = b * 256 + tid;
        if (node < N_NODES) {
            cnt_out[node] = v;
            row_start[node] = gb + eb;
        }
    }
    __syncthreads();

    // ---- scatter into per-node CSR segments: ~4 iters ----
    for (int i = tid; i < n; i += 1024) {
        unsigned e = staged[i];
        int r = (int)(e >> 17);
        int k = atomicAdd(&run[r], 1);
        sorted_src[gb + ebase[r] + k] = (int)(e & 0x1FFFFu);
    }
}

// ---------------------------------------------------------------------------
// Gather aggregation (r1 version, verbatim — measured best): 8 nodes/wave,
// 8 lanes/node, 16B/lane. One global_load_dwordx4 retires 8 edges per wave
// instruction. Edge indices: coalesced per-lane load + ds_bpermute broadcast
// within the 8-lane group. Consecutive nodes -> contiguous self-rows / index
// segments / output store. Tail edges pad to zeroed dummy row N_NODES.
// ---------------------------------------------------------------------------
__global__ __launch_bounds__(256) void aggregate_kernel(
    const u16* __restrict__ xb, const int* __restrict__ cnt_arr,
    const int* __restrict__ row_start, const int* __restrict__ sorted_src,
    u16* __restrict__ xa)
{
    int tid  = threadIdx.x;
    int lane = tid & 63;
    int w    = tid >> 6;
    int g    = lane >> 3;        // group (node within wave)
    int k    = lane & 7;         // 16B chunk within row / edge slot in batch
    int node = blockIdx.x * 32 + w * 8 + g;   // 3125 blocks * 32 = 100000 exact

    int cnt  = cnt_arr[node];
    int base = row_start[node];

    // self-row init: acc = x[node]  (accl[i]=col k*8+2i, acch[i]=col k*8+2i+1)
    const uint4 sv = *(const uint4*)(xb + ((size_t)node * D + k * 8));
    float accl[4], acch[4];
#pragma unroll
    for (int i = 0; i < 4; ++i) {
        unsigned d = ((const unsigned*)&sv)[i];
        unsigned lo = d << 16, hi = d & 0xFFFF0000u;
        __builtin_memcpy(&accl[i], &lo, 4);
        __builtin_memcpy(&acch[i], &hi, 4);
    }

    // wave max degree across the 8 groups -> common trip count
    int mc = cnt;
    mc = max(mc, __shfl_xor(mc, 8));
    mc = max(mc, __shfl_xor(mc, 16));
    mc = max(mc, __shfl_xor(mc, 32));

    int lb4 = (lane & 56) << 2;  // byte addr of group's lane 0 for bpermute

    for (int c = 0; c < mc; c += 8) {
        // lane k holds edge c+k's source index for its group;
        // past-degree slots point at the zeroed dummy row N_NODES.
        int s = (c + k < cnt) ? sorted_src[base + c + k] : N_NODES;

        uint4 v[8];
#pragma unroll
        for (int j = 0; j < 8; ++j) {
            int idx = __builtin_amdgcn_ds_bpermute(lb4 + 4 * j, s);
            v[j] = *(const uint4*)(xb + (((size_t)(unsigned)idx) * D + (k << 3)));
        }
#pragma unroll
        for (int j = 0; j < 8; ++j) {
#pragma unroll
            for (int i = 0; i < 4; ++i) {
                unsigned d = ((const unsigned*)&v[j])[i];
                unsigned lo = d << 16, hi = d & 0xFFFF0000u;
                float fl, fh;
                __builtin_memcpy(&fl, &lo, 4);
                __builtin_memcpy(&fh, &hi, 4);
                accl[i] += fl;
                acch[i] += fh;
            }
        }
    }

    // pack to bf16 pairs and store this lane's 16B of the row
    unsigned out[4];
#pragma unroll
    for (int i = 0; i < 4; ++i) {
        unsigned b0 = f2bf(accl[i]);
        unsigned b1 = f2bf(acch[i]);
        out[i] = b0 | (b1 << 16);
    }
    *(uint4*)(xa + ((size_t)node * D + k * 8)) = *(const uint4*)out;
}

// ---------------------------------------------------------------------------
// MFMA MLP: out = [relu?]( relu(xa@W1+b1) @ W2 + b2 ), bf16 in, fp32 acc.
// Block = 256 = 4 waves; wave = 16 nodes x all 64 cols.
// A-frags (A[m=lane&15][k=quad*8+j], m120-verified) load DIRECTLY from
// global xa: one dwordx4 per K-half (wave covers a contiguous 2KB window).
// B-frags: prepacked Wf, one dwordx4 per frag. C/D layout (m89-verified):
// col=lane&15, row=quad*4+reg. Hidden u round-trips through WAVE-PRIVATE
// LDS rows (stride 136B -> layer-2 A-frag ds_read_b64 pairs, <=4-way
// aliased); no __syncthreads needed.
// ---------------------------------------------------------------------------
#define US 68   // u16 stride per node row (136 B)

template <int WRITE_BF16>
__global__ __launch_bounds__(256) void gin_mlp_kernel(
    const u16* __restrict__ xa, const u16* __restrict__ Wf,
    const float* __restrict__ b1, const float* __restrict__ b2,
    float* __restrict__ outf, u16* __restrict__ outb)
{
    __shared__ u16 us[64 * US];   // 8704 B

    int tid  = threadIdx.x;
    int lane = tid & 63;
    int w    = tid >> 6;
    int quad = lane >> 4;
    int l16  = lane & 15;
    int n0   = blockIdx.x * 64 + w * 16;

    // ---- layer 1: u = relu(xa @ W1 + b1) ----
    int arow = min(n0 + l16, N_NODES - 1);
    const u16* ab = xa + (size_t)arow * D + quad * 8;
    bf16x8 a0 = *(const bf16x8*)ab;          // k = quad*8+j
    bf16x8 a1 = *(const bf16x8*)(ab + 32);   // k = 32+quad*8+j

    f32x4 acc[4];
#pragma unroll
    for (int ct = 0; ct < 4; ++ct) {
        float bv = b1[ct * 16 + l16];
        acc[ct] = (f32x4){bv, bv, bv, bv};
        bf16x8 bf0 = *(const bf16x8*)(Wf + (size_t)((0 * 4 + ct) * 2 + 0) * 512 + lane * 8);
        bf16x8 bf1 = *(const bf16x8*)(Wf + (size_t)((0 * 4 + ct) * 2 + 1) * 512 + lane * 8);
        acc[ct] = __builtin_amdgcn_mfma_f32_16x16x32_bf16(a0, bf0, acc[ct], 0, 0, 0);
        acc[ct] = __builtin_amdgcn_mfma_f32_16x16x32_bf16(a1, bf1, acc[ct], 0, 0, 0);
    }

    // relu -> bf16 -> wave-private LDS rows (C-layout: row=quad*4+r, col)
#pragma unroll
    for (int ct = 0; ct < 4; ++ct)
#pragma unroll
        for (int r = 0; r < 4; ++r)
            us[(w * 16 + quad * 4 + r) * US + ct * 16 + l16] =
                f2bf(fmaxf(acc[ct][r], 0.f));

    // ---- layer 2: v = u @ W2 + b2 ----
    const u16* ub = &us[(w * 16 + l16) * US + quad * 8];
    s16x4 lo0 = *(const s16x4*)ub;
    s16x4 hi0 = *(const s16x4*)(ub + 4);
    s16x4 lo1 = *(const s16x4*)(ub + 32);
    s16x4 hi1 = *(const s16x4*)(ub + 36);
    bf16x8 u0 = __builtin_shufflevector(lo0, hi0, 0, 1, 2, 3, 4, 5, 6, 7);
    bf16x8 u1 = __builtin_shufflevector(lo1, hi1, 0, 1, 2, 3, 4, 5, 6, 7);

#pragma unroll
    for (int ct = 0; ct < 4; ++ct) {
        float bv = b2[ct * 16 + l16];
        acc[ct] = (f32x4){bv, bv, bv, bv};
        bf16x8 bf0 = *(const bf16x8*)(Wf + (size_t)((1 * 4 + ct) * 2 + 0) * 512 + lane * 8);
        bf16x8 bf1 = *(const bf16x8*)(Wf + (size_t)((1 * 4 + ct) * 2 + 1) * 512 + lane * 8);
        acc[ct] = __builtin_amdgcn_mfma_f32_16x16x32_bf16(u0, bf0, acc[ct], 0, 0, 0);
        acc[ct] = __builtin_amdgcn_mfma_f32_16x16x32_bf16(u1, bf1, acc[ct], 0, 0, 0);
    }

    // epilogue (C-layout scatter; 16-lane groups write contiguous runs)
#pragma unroll
    for (int r = 0; r < 4; ++r) {
        int node = n0 + quad * 4 + r;
        if (node >= N_NODES) continue;
#pragma unroll
        for (int ct = 0; ct < 4; ++ct) {
            if (WRITE_BF16)
                outb[(size_t)node * D + ct * 16 + l16] = f2bf(fmaxf(acc[ct][r], 0.f));
            else
                outf[(size_t)node * D + ct * 16 + l16] = acc[ct][r];
        }
    }
}

extern "C" void kernel_launch(void* const* d_in, const int* in_sizes, int n_in,
                              void* d_out, int out_size, void* d_ws, size_t ws_size,
                              hipStream_t stream)
{
    const float* x  = (const float*)d_in[0];
    const int*   ei = (const int*)d_in[1];
    const float* W1 = (const float*)d_in[2];
    const float* b1 = (const float*)d_in[3];
    const float* W2 = (const float*)d_in[4];
    const float* b2 = (const float*)d_in[5];
    float* out = (float*)d_out;

    // workspace (~41.5 MB):
    //   qtail(512) | cnt(100096) | row_start(100096)
    //   queue (391*4800 u32) | sorted_src (391*4800 int)
    //   Wf (8192 u16) | xa (N rows bf16) | xb ((N+1) rows bf16, also holds hb)
    int* qtail      = (int*)d_ws;
    int* cnt_arr    = qtail + 512;
    int* row_start  = cnt_arr + 100096;
    unsigned* queue = (unsigned*)(row_start + 100096);
    int* sorted_src = (int*)(queue + (size_t)NBUCKET * QCAP_B);
    u16* Wf         = (u16*)(sorted_src + (size_t)NBUCKET * QCAP_B);
    u16* xa_b       = Wf + 8192;
    u16* xb_b       = xa_b + (size_t)N_NODES * D;

    const int agg_blocks = (N_NODES + 31) / 32;     // 3125 (8 nodes/wave)
    const int mlp_blocks = (N_NODES + 63) / 64;     // 1563

    // ---- prep (fused into convert): x -> bf16, qtail zero, dummy row,
    //      weight pack ----
    convert_kernel<<<6251, 256, 0, stream>>>(x, xb_b, W1, W2, Wf, qtail);
    sort_kernel<<<SORT_BLOCKS, 1024, 0, stream>>>(ei, qtail, queue);
    bin3_kernel<<<NBUCKET, 1024, 0, stream>>>(queue, qtail, cnt_arr, row_start, sorted_src);

    // ---- layer 1: hb(xb_b) = relu(MLP(xb + gather(xb))) ----
    aggregate_kernel<<<agg_blocks, 256, 0, stream>>>(xb_b, cnt_arr, row_start, sorted_src, xa_b);
    gin_mlp_kernel<1><<<mlp_blocks, 256, 0, stream>>>(xa_b, Wf, b1, b2, nullptr, xb_b);

    // ---- layer 2: out = MLP(hb + gather(hb)) ----
    aggregate_kernel<<<agg_blocks, 256, 0, stream>>>(xb_b, cnt_arr, row_start, sorted_src, xa_b);
    gin_mlp_kernel<0><<<mlp_blocks, 256, 0, stream>>>(xa_b, Wf, b1, b2, out, nullptr);
}